// Round 1
// baseline (1726.673 us; speedup 1.0000x reference)
//
#include <hip/hip_runtime.h>
#include <stdint.h>

#define TT 8
#define NN 40000
#define FF 256
#define EE 640000
#define BB 1024
#define ROWS 320000   // TT*NN

typedef __attribute__((ext_vector_type(8))) short s16x8;
typedef __attribute__((ext_vector_type(4))) float f32x4;

__device__ __forceinline__ unsigned short f2bf(float f){
  unsigned int u = __float_as_uint(f);
  u += 0x7fffu + ((u >> 16) & 1u);
  return (unsigned short)(u >> 16);
}
__device__ __forceinline__ float bflo(unsigned int u){ return __uint_as_float(u << 16); }
__device__ __forceinline__ float bfhi(unsigned int u){ return __uint_as_float(u & 0xffff0000u); }

// global -> LDS direct DMA, 16B per lane. LDS dest must be wave-uniform base + lane*16.
__device__ __forceinline__ void gl2lds16(const void* g, void* l){
  auto gp = reinterpret_cast<const unsigned int __attribute__((address_space(1)))*>(
      reinterpret_cast<uintptr_t>(g));
  auto lp = reinterpret_cast<unsigned int __attribute__((address_space(3)))*>(
      static_cast<unsigned int>(reinterpret_cast<uintptr_t>(l)));
  __builtin_amdgcn_global_load_lds(gp, lp, 16, 0, 0);
}

// ---------------- weight prep: transpose/convert to bf16 ----------------
__global__ void prep_k(const float* __restrict__ proj_w, const float* __restrict__ w1,
                       const float* __restrict__ w2, const float* __restrict__ wih,
                       const float* __restrict__ whh,
                       unsigned short* __restrict__ projwt, unsigned short* __restrict__ w1t,
                       unsigned short* __restrict__ w2t, unsigned short* __restrict__ wihb,
                       uint2* __restrict__ whhp)
{
  int i = blockIdx.x * 256 + threadIdx.x;
  if (i < 32768) {                      // projwt[p][f] = proj_w[f][p]
    int p = i >> 8, f = i & 255;
    projwt[i] = f2bf(proj_w[f * 128 + p]);
  } else if (i < 49152) {               // w1t[o][c] = w1[c][o]
    int k = i - 32768; int o = k >> 7, c = k & 127;
    w1t[k] = f2bf(w1[c * 128 + o]);
  } else if (i < 65536) {
    int k = i - 49152; int o = k >> 7, c = k & 127;
    w2t[k] = f2bf(w2[c * 128 + o]);
  } else if (i < 163840) {              // wihb = w_ih as-is (rows are output cols)
    int k = i - 65536;
    wihb[k] = f2bf(wih[k]);
  } else if (i < 180224) {              // whhp[k][j] = {whh[j][k], whh[128+j][k], whh[256+j][k], 0}
    int k = i - 163840; int kk = k >> 7, j = k & 127;
    unsigned int lo = (unsigned int)f2bf(whh[j * 128 + kk]) |
                      ((unsigned int)f2bf(whh[(128 + j) * 128 + kk]) << 16);
    unsigned int hi = (unsigned int)f2bf(whh[(256 + j) * 128 + kk]);
    whhp[k] = make_uint2(lo, hi);
  }
}

// ---------------- CSR build ----------------
__global__ void init_k(int* __restrict__ counts, int* __restrict__ fill){
  int i = blockIdx.x * 256 + threadIdx.x;
  if (i < NN) { counts[i] = 0; fill[i] = 0; }
}
__global__ void count_k(const int* __restrict__ dst, int* __restrict__ counts){
  int i = blockIdx.x * 256 + threadIdx.x;
  if (i < EE) atomicAdd(&counts[dst[i]], 1);
}
__global__ void scan_k(const int* __restrict__ counts, int* __restrict__ rp,
                       float* __restrict__ dinv)
{
  __shared__ int sums[1024];
  const int CH = 40;
  int t = threadIdx.x;
  int beg = t * CH, end = beg + CH; if (end > NN) end = NN; if (beg > NN) beg = NN;
  int s = 0;
  for (int i = beg; i < end; i++) s += counts[i];
  sums[t] = s;
  __syncthreads();
  for (int off = 1; off < 1024; off <<= 1) {
    int add = (t >= off) ? sums[t - off] : 0;
    __syncthreads();
    sums[t] += add;
    __syncthreads();
  }
  int run = sums[t] - s;   // exclusive prefix for this chunk
  for (int i = beg; i < end; i++) { rp[i] = run; run += counts[i]; }
  if (t == 1023) rp[NN] = sums[1023];
  for (int i = beg; i < end; i++) dinv[i] = rsqrtf((float)(counts[i] + 1));
}
__global__ void fill_k(const int* __restrict__ src, const int* __restrict__ dst,
                       const int* __restrict__ rp, int* __restrict__ fill,
                       int* __restrict__ ci)
{
  int i = blockIdx.x * 256 + threadIdx.x;
  if (i < EE) {
    int d = dst[i];
    int pos = rp[d] + atomicAdd(&fill[d], 1);
    ci[pos] = src[i];
  }
}

// ---------------- tiled MFMA GEMM: C[r][c] = sum_k A[r][k]*Bt[c][k] ----------------
// AF32: A is fp32 (converted to bf16 in stager); else A is bf16 (global_load_lds).
// MODE 0: bf16 out = relu(acc + bias[col]);  MODE 1: bf16 out = acc*dinv[row%NN];
// MODE 2: f32 out = acc.
template<int AF32, int MODE>
__global__ __launch_bounds__(256)
void gemm_k(const void* __restrict__ Ap, const short* __restrict__ Bt,
            void* __restrict__ Cp, int K, int ldc,
            const float* __restrict__ bias, const float* __restrict__ dinv)
{
  __shared__ short lA[128 * 64];
  __shared__ short lB[128 * 64];
  const int tid = threadIdx.x;
  const int lane = tid & 63, wave = tid >> 6;
  const int row0 = blockIdx.x * 128;
  const int col0 = blockIdx.y * 128;
  const int qr = (wave & 1) * 64, qc = (wave >> 1) * 64;
  const int m = lane & 15, q = lane >> 4;

  f32x4 acc[4][4];
#pragma unroll
  for (int i = 0; i < 4; i++)
#pragma unroll
    for (int j = 0; j < 4; j++) acc[i][j] = (f32x4){0.f, 0.f, 0.f, 0.f};

  for (int k0 = 0; k0 < K; k0 += 64) {
    __syncthreads();
    if (AF32) {
      const float* A = (const float*)Ap;
      int row = tid >> 1, half = tid & 1;
      const float* gp = A + (size_t)(row0 + row) * K + k0 + half * 32;
#pragma unroll
      for (int gi = 0; gi < 4; gi++) {
        float4 v0 = *(const float4*)(gp + gi * 8);
        float4 v1 = *(const float4*)(gp + gi * 8 + 4);
        uint4 w;
        w.x = (unsigned)f2bf(v0.x) | ((unsigned)f2bf(v0.y) << 16);
        w.y = (unsigned)f2bf(v0.z) | ((unsigned)f2bf(v0.w) << 16);
        w.z = (unsigned)f2bf(v1.x) | ((unsigned)f2bf(v1.y) << 16);
        w.w = (unsigned)f2bf(v1.z) | ((unsigned)f2bf(v1.w) << 16);
        int g = half * 4 + gi;
        *(uint4*)&lA[row * 64 + ((g ^ (row & 7)) * 8)] = w;
      }
    } else {
      const short* A = (const short*)Ap;
#pragma unroll
      for (int i = 0; i < 4; i++) {
        int c = wave * 4 + i;
        int row = c * 8 + (lane >> 3);
        int kg = (lane & 7) ^ (row & 7);
        gl2lds16(A + (size_t)(row0 + row) * K + k0 + kg * 8, lA + c * 512);
      }
    }
#pragma unroll
    for (int i = 0; i < 4; i++) {
      int c = wave * 4 + i;
      int row = c * 8 + (lane >> 3);
      int kg = (lane & 7) ^ (row & 7);
      gl2lds16(Bt + (size_t)(col0 + row) * K + k0 + kg * 8, lB + c * 512);
    }
    __syncthreads();
#pragma unroll
    for (int ks = 0; ks < 2; ks++) {
      s16x8 af[4], bf[4];
#pragma unroll
      for (int i = 0; i < 4; i++) {
        int R = qr + 16 * i + m;
        af[i] = *(const s16x8*)&lA[R * 64 + (((ks * 4 + q) ^ (R & 7)) * 8)];
        int RB = qc + 16 * i + m;
        bf[i] = *(const s16x8*)&lB[RB * 64 + (((ks * 4 + q) ^ (RB & 7)) * 8)];
      }
#pragma unroll
      for (int i = 0; i < 4; i++)
#pragma unroll
        for (int j = 0; j < 4; j++)
          acc[i][j] = __builtin_amdgcn_mfma_f32_16x16x32_bf16(af[i], bf[j], acc[i][j], 0, 0, 0);
    }
  }
#pragma unroll
  for (int i = 0; i < 4; i++) {
    int rbase = row0 + qr + 16 * i + q * 4;
#pragma unroll
    for (int j = 0; j < 4; j++) {
      int col = col0 + qc + 16 * j + m;
#pragma unroll
      for (int rr = 0; rr < 4; rr++) {
        int rg = rbase + rr;
        float v = acc[i][j][rr];
        if (MODE == 0) {
          v += bias[col]; v = fmaxf(v, 0.f);
          ((unsigned short*)Cp)[(size_t)rg * ldc + col] = f2bf(v);
        } else if (MODE == 1) {
          v *= dinv[rg % NN];
          ((unsigned short*)Cp)[(size_t)rg * ldc + col] = f2bf(v);
        } else {
          ((float*)Cp)[(size_t)rg * ldc + col] = v;
        }
      }
    }
  }
}

// ---------------- GCN aggregation: one wave per (t,node), 2 features/lane ----------------
__global__ __launch_bounds__(256)
void agg_k(const unsigned int* __restrict__ Ms, unsigned int* __restrict__ Hout,
           const int* __restrict__ rp, const int* __restrict__ ci,
           const float* __restrict__ dinv, const float* __restrict__ bias)
{
  int widx = blockIdx.x * 4 + (threadIdx.x >> 6);
  int lane = threadIdx.x & 63;
  int t = widx / NN;
  int v = widx - t * NN;
  const unsigned int* base = Ms + (size_t)t * NN * 64;
  unsigned int u = base[(size_t)v * 64 + lane];   // self loop term (dinv[v]*m[v])
  float a0 = bflo(u), a1 = bfhi(u);
  int e0 = rp[v], e1 = rp[v + 1];
  for (int e = e0; e < e1; e++) {
    int s = ci[e];
    unsigned int w = base[(size_t)s * 64 + lane];
    a0 += bflo(w); a1 += bfhi(w);
  }
  float dv = dinv[v];
  float b0 = bias[lane * 2], b1 = bias[lane * 2 + 1];
  a0 = fmaxf(dv * a0 + b0, 0.f);
  a1 = fmaxf(dv * a1 + b1, 0.f);
  Hout[(size_t)widx * 64 + lane] = (unsigned int)f2bf(a0) | ((unsigned int)f2bf(a1) << 16);
}

// ---------------- gather target embeddings -> TGT (bf16, [t][b][256]) ----------------
__global__ void gather_k(const unsigned int* __restrict__ h1, const unsigned int* __restrict__ h2,
                         const int* __restrict__ tix, unsigned int* __restrict__ TGT)
{
  int i = blockIdx.x * 256 + threadIdx.x;   // over 8*1024*128 dwords
  int dw = i & 127; int r = i >> 7; int b = r & 1023; int t = r >> 10;
  int node = tix[b];
  size_t src = ((size_t)t * NN + node) * 64 + (dw & 63);
  unsigned int val = (dw < 64) ? h1[src] : h2[src];
  TGT[(size_t)r * 128 + dw] = val;
}

// ---------------- GRU recurrence + attention (rows independent across B) ----------------
__global__ __launch_bounds__(256)
void gru_attn_k(const float* __restrict__ GI, const uint2* __restrict__ Whp,
                const float* __restrict__ b_ih, const float* __restrict__ b_hh,
                const float* __restrict__ attw, const float* __restrict__ attb,
                float* __restrict__ rep, float* __restrict__ out_attn)
{
  __shared__ float hbuf[2][128];
  __shared__ float red[2][2];
  __shared__ float sc[2][8];
  int tid = threadIdx.x;
  int r = tid >> 7, j = tid & 127;
  int lane = tid & 63, wv = tid >> 6;
  int b = blockIdx.x * 2 + r;
  hbuf[r][j] = 0.f;
  float bi0 = b_ih[j], bi1 = b_ih[128 + j], bi2 = b_ih[256 + j];
  float bh0 = b_hh[j], bh1 = b_hh[128 + j], bh2 = b_hh[256 + j];
  float aw = attw[j], ab = attb[0];
  float ht[8];
  __syncthreads();
  for (int t = 0; t < 8; t++) {
    const float* gi = GI + ((size_t)(t * 1024 + b)) * 384;
    float accr = bh0, accz = bh1, accg = bh2;
#pragma unroll 4
    for (int k = 0; k < 128; k++) {
      float hk = hbuf[r][k];
      uint2 wp = Whp[k * 128 + j];
      accr += hk * bflo(wp.x);
      accz += hk * bfhi(wp.x);
      accg += hk * bflo(wp.y);
    }
    float x0 = gi[j] + bi0, x1 = gi[128 + j] + bi1, x2 = gi[256 + j] + bi2;
    float rg = 1.f / (1.f + __expf(-(x0 + accr)));
    float z  = 1.f / (1.f + __expf(-(x1 + accz)));
    float g  = tanhf(x2 + rg * accg);
    float hp = hbuf[r][j];
    float hn = (1.f - z) * g + z * hp;
    __syncthreads();
    hbuf[r][j] = hn;
    float p = hn * aw;
    for (int off = 32; off; off >>= 1) p += __shfl_down(p, off, 64);
    if (lane == 0) red[wv >> 1][wv & 1] = p;
    __syncthreads();
    if (j == 0) sc[r][t] = tanhf(red[r][0] + red[r][1] + ab);
    ht[t] = hn;
  }
  __syncthreads();
  float s[8], mx = -1e30f;
#pragma unroll
  for (int t = 0; t < 8; t++) { s[t] = sc[r][t]; mx = fmaxf(mx, s[t]); }
  float sum = 0.f;
#pragma unroll
  for (int t = 0; t < 8; t++) { s[t] = __expf(s[t] - mx); sum += s[t]; }
  float inv = 1.f / sum;
  float rv = 0.f;
#pragma unroll
  for (int t = 0; t < 8; t++) rv += s[t] * inv * ht[t];
  rep[(size_t)b * 128 + j] = rv;
  if (j < 8) out_attn[b * 8 + j] = s[j] * inv;
}

// ---------------- final MLP ----------------
__global__ void pred_k(const float* __restrict__ rep, const float* __restrict__ w1,
                       const float* __restrict__ b1, const float* __restrict__ w2,
                       const float* __restrict__ b2, float* __restrict__ out)
{
  int bidx = blockIdx.x * 256 + threadIdx.x;
  if (bidx >= 1024) return;
  const float* rp = rep + (size_t)bidx * 128;
  float acc[16];
#pragma unroll
  for (int i = 0; i < 16; i++) acc[i] = b1[i];
  for (int k = 0; k < 128; k++) {
    float rv = rp[k];
#pragma unroll
    for (int i = 0; i < 16; i++) acc[i] += rv * w1[k * 16 + i];
  }
  float pv = b2[0];
#pragma unroll
  for (int i = 0; i < 16; i++) pv += fmaxf(acc[i], 0.f) * w2[i];
  out[bidx] = pv;
}

extern "C" void kernel_launch(void* const* d_in, const int* in_sizes, int n_in,
                              void* d_out, int out_size, void* d_ws, size_t ws_size,
                              hipStream_t stream)
{
  (void)in_sizes; (void)n_in; (void)out_size; (void)ws_size;
  const float* x      = (const float*)d_in[0];
  const int*   ei     = (const int*)d_in[1];
  const int*   tix    = (const int*)d_in[2];
  const float* proj_w = (const float*)d_in[3];
  const float* proj_b = (const float*)d_in[4];
  const float* gcn_w1 = (const float*)d_in[5];
  const float* gcn_b1 = (const float*)d_in[6];
  const float* gcn_w2 = (const float*)d_in[7];
  const float* gcn_b2 = (const float*)d_in[8];
  const float* w_ih   = (const float*)d_in[9];
  const float* w_hh   = (const float*)d_in[10];
  const float* b_ih   = (const float*)d_in[11];
  const float* b_hh   = (const float*)d_in[12];
  const float* attw   = (const float*)d_in[13];
  const float* attb   = (const float*)d_in[14];
  const float* pw1    = (const float*)d_in[15];
  const float* pb1    = (const float*)d_in[16];
  const float* pw2    = (const float*)d_in[17];
  const float* pb2    = (const float*)d_in[18];
  float* out = (float*)d_out;

  char* ws = (char*)d_ws;
  size_t off = 0;
  auto alloc = [&](size_t bytes) -> char* {
    char* p = ws + off; off += (bytes + 255) & ~(size_t)255; return p;
  };
  int*   counts = (int*)alloc((size_t)NN * 4);
  int*   fill   = (int*)alloc((size_t)NN * 4);
  int*   rp     = (int*)alloc((size_t)(NN + 1) * 4);
  float* dinv   = (float*)alloc((size_t)NN * 4);
  int*   ci     = (int*)alloc((size_t)EE * 4);
  unsigned short* projwt = (unsigned short*)alloc(128 * 256 * 2);
  unsigned short* w1t    = (unsigned short*)alloc(128 * 128 * 2);
  unsigned short* w2t    = (unsigned short*)alloc(128 * 128 * 2);
  unsigned short* wihb   = (unsigned short*)alloc(384 * 256 * 2);
  uint2* whhp            = (uint2*)alloc(128 * 128 * 8);
  unsigned int* TGT = (unsigned int*)alloc((size_t)8192 * 256 * 2);
  float* GI  = (float*)alloc((size_t)8192 * 384 * 4);
  float* rep = (float*)alloc((size_t)1024 * 128 * 4);
  unsigned short* bufA = (unsigned short*)alloc((size_t)ROWS * 128 * 2); // Hp, then h2
  unsigned short* bufB = (unsigned short*)alloc((size_t)ROWS * 128 * 2); // Ms1, then Ms2
  unsigned short* bufC = (unsigned short*)alloc((size_t)ROWS * 128 * 2); // h1

  const int* e_src = ei;
  const int* e_dst = ei + EE;

  prep_k<<<704, 256, 0, stream>>>(proj_w, gcn_w1, gcn_w2, w_ih, w_hh,
                                  projwt, w1t, w2t, wihb, whhp);
  init_k<<<157, 256, 0, stream>>>(counts, fill);
  count_k<<<2500, 256, 0, stream>>>(e_dst, counts);
  scan_k<<<1, 1024, 0, stream>>>(counts, rp, dinv);
  fill_k<<<2500, 256, 0, stream>>>(e_src, e_dst, rp, fill, ci);

  // proj: Hp = relu(x @ proj_w + b)   (fp32 A, bf16 out)
  gemm_k<1, 0><<<dim3(2500, 1), 256, 0, stream>>>(x, (const short*)projwt, bufA,
                                                  256, 128, proj_b, nullptr);
  // gcn1 matmul: Ms1 = dinv[row] * (Hp @ w1)
  gemm_k<0, 1><<<dim3(2500, 1), 256, 0, stream>>>(bufA, (const short*)w1t, bufB,
                                                  128, 128, nullptr, dinv);
  // gcn1 aggregate -> h1
  agg_k<<<80000, 256, 0, stream>>>((const unsigned int*)bufB, (unsigned int*)bufC,
                                   rp, ci, dinv, gcn_b1);
  // gcn2 matmul: Ms2 = dinv[row] * (h1 @ w2)
  gemm_k<0, 1><<<dim3(2500, 1), 256, 0, stream>>>(bufC, (const short*)w2t, bufB,
                                                  128, 128, nullptr, dinv);
  // gcn2 aggregate -> h2
  agg_k<<<80000, 256, 0, stream>>>((const unsigned int*)bufB, (unsigned int*)bufA,
                                   rp, ci, dinv, gcn_b2);
  // gather targets -> TGT
  gather_k<<<4096, 256, 0, stream>>>((const unsigned int*)bufC, (const unsigned int*)bufA,
                                     tix, TGT);
  // GI = TGT @ w_ih^T  (fp32 out)
  gemm_k<0, 2><<<dim3(64, 3), 256, 0, stream>>>(TGT, (const short*)wihb, GI,
                                                256, 384, nullptr, nullptr);
  // GRU + attention
  gru_attn_k<<<512, 256, 0, stream>>>(GI, whhp, b_ih, b_hh, attw, attb, rep, out + 1024);
  // prediction MLP
  pred_k<<<4, 256, 0, stream>>>(rep, pw1, pb1, pw2, pb2, out);
}

// Round 2
// 1228.564 us; speedup vs baseline: 1.4054x; 1.4054x over previous
//
#include <hip/hip_runtime.h>
#include <stdint.h>

#define TT 8
#define NN 40000
#define FF 256
#define EE 640000
#define BB 1024
#define ROWS 320000   // TT*NN

typedef __attribute__((ext_vector_type(8))) short s16x8;
typedef __attribute__((ext_vector_type(4))) float f32x4;

__device__ __forceinline__ unsigned short f2bf(float f){
  unsigned int u = __float_as_uint(f);
  u += 0x7fffu + ((u >> 16) & 1u);
  return (unsigned short)(u >> 16);
}
__device__ __forceinline__ float bflo(unsigned int u){ return __uint_as_float(u << 16); }
__device__ __forceinline__ float bfhi(unsigned int u){ return __uint_as_float(u & 0xffff0000u); }

// global -> LDS direct DMA, 16B per lane. LDS dest must be wave-uniform base + lane*16.
__device__ __forceinline__ void gl2lds16(const void* g, void* l){
  auto gp = reinterpret_cast<const unsigned int __attribute__((address_space(1)))*>(
      reinterpret_cast<uintptr_t>(g));
  auto lp = reinterpret_cast<unsigned int __attribute__((address_space(3)))*>(
      static_cast<unsigned int>(reinterpret_cast<uintptr_t>(l)));
  __builtin_amdgcn_global_load_lds(gp, lp, 16, 0, 0);
}

// ---------------- weight prep: transpose/convert to bf16 ----------------
__global__ void prep_k(const float* __restrict__ proj_w, const float* __restrict__ w1,
                       const float* __restrict__ w2, const float* __restrict__ wih,
                       const float* __restrict__ whh,
                       unsigned short* __restrict__ projwt, unsigned short* __restrict__ w1t,
                       unsigned short* __restrict__ w2t, unsigned short* __restrict__ wihb,
                       uint2* __restrict__ whhp)
{
  int i = blockIdx.x * 256 + threadIdx.x;
  if (i < 32768) {                      // projwt[p][f] = proj_w[f][p]
    int p = i >> 8, f = i & 255;
    projwt[i] = f2bf(proj_w[f * 128 + p]);
  } else if (i < 49152) {               // w1t[o][c] = w1[c][o]
    int k = i - 32768; int o = k >> 7, c = k & 127;
    w1t[k] = f2bf(w1[c * 128 + o]);
  } else if (i < 65536) {
    int k = i - 49152; int o = k >> 7, c = k & 127;
    w2t[k] = f2bf(w2[c * 128 + o]);
  } else if (i < 163840) {              // wihb = w_ih as-is (rows are output cols)
    int k = i - 65536;
    wihb[k] = f2bf(wih[k]);
  } else if (i < 180224) {              // whhp[k][j] = {whh[j][k], whh[128+j][k], whh[256+j][k], 0}
    int k = i - 163840; int kk = k >> 7, j = k & 127;
    unsigned int lo = (unsigned int)f2bf(whh[j * 128 + kk]) |
                      ((unsigned int)f2bf(whh[(128 + j) * 128 + kk]) << 16);
    unsigned int hi = (unsigned int)f2bf(whh[(256 + j) * 128 + kk]);
    whhp[k] = make_uint2(lo, hi);
  }
}

// ---------------- CSR build ----------------
__global__ void init_k(int* __restrict__ counts, int* __restrict__ fill){
  int i = blockIdx.x * 256 + threadIdx.x;
  if (i < NN) { counts[i] = 0; fill[i] = 0; }
}
__global__ void count_k(const int* __restrict__ dst, int* __restrict__ counts){
  int i = blockIdx.x * 256 + threadIdx.x;
  if (i < EE) atomicAdd(&counts[dst[i]], 1);
}
__global__ void scan_k(const int* __restrict__ counts, int* __restrict__ rp,
                       float* __restrict__ dinv)
{
  __shared__ int sums[1024];
  const int CH = 40;
  int t = threadIdx.x;
  int beg = t * CH, end = beg + CH; if (end > NN) end = NN; if (beg > NN) beg = NN;
  int s = 0;
  for (int i = beg; i < end; i++) s += counts[i];
  sums[t] = s;
  __syncthreads();
  for (int off = 1; off < 1024; off <<= 1) {
    int add = (t >= off) ? sums[t - off] : 0;
    __syncthreads();
    sums[t] += add;
    __syncthreads();
  }
  int run = sums[t] - s;   // exclusive prefix for this chunk
  for (int i = beg; i < end; i++) { rp[i] = run; run += counts[i]; }
  if (t == 1023) rp[NN] = sums[1023];
  for (int i = beg; i < end; i++) dinv[i] = rsqrtf((float)(counts[i] + 1));
}
__global__ void fill_k(const int* __restrict__ src, const int* __restrict__ dst,
                       const int* __restrict__ rp, int* __restrict__ fill,
                       int* __restrict__ ci)
{
  int i = blockIdx.x * 256 + threadIdx.x;
  if (i < EE) {
    int d = dst[i];
    int pos = rp[d] + atomicAdd(&fill[d], 1);
    ci[pos] = src[i];
  }
}

// ---------------- tiled MFMA GEMM: C[r][c] = sum_k A[r][k]*Bt[c][k] ----------------
// AF32: A is fp32 (converted to bf16 in stager); else A is bf16 (global_load_lds).
// MODE 0: bf16 out = relu(acc + bias[col]);  MODE 1: bf16 out = acc*dinv[row%NN];
// MODE 2: f32 out = acc.
template<int AF32, int MODE>
__global__ __launch_bounds__(256)
void gemm_k(const void* __restrict__ Ap, const short* __restrict__ Bt,
            void* __restrict__ Cp, int K, int ldc,
            const float* __restrict__ bias, const float* __restrict__ dinv)
{
  __shared__ short lA[128 * 64];
  __shared__ short lB[128 * 64];
  const int tid = threadIdx.x;
  const int lane = tid & 63, wave = tid >> 6;
  const int row0 = blockIdx.x * 128;
  const int col0 = blockIdx.y * 128;
  const int qr = (wave & 1) * 64, qc = (wave >> 1) * 64;
  const int m = lane & 15, q = lane >> 4;

  f32x4 acc[4][4];
#pragma unroll
  for (int i = 0; i < 4; i++)
#pragma unroll
    for (int j = 0; j < 4; j++) acc[i][j] = (f32x4){0.f, 0.f, 0.f, 0.f};

  for (int k0 = 0; k0 < K; k0 += 64) {
    __syncthreads();
    if (AF32) {
      const float* A = (const float*)Ap;
      int row = tid >> 1, half = tid & 1;
      const float* gp = A + (size_t)(row0 + row) * K + k0 + half * 32;
#pragma unroll
      for (int gi = 0; gi < 4; gi++) {
        float4 v0 = *(const float4*)(gp + gi * 8);
        float4 v1 = *(const float4*)(gp + gi * 8 + 4);
        uint4 w;
        w.x = (unsigned)f2bf(v0.x) | ((unsigned)f2bf(v0.y) << 16);
        w.y = (unsigned)f2bf(v0.z) | ((unsigned)f2bf(v0.w) << 16);
        w.z = (unsigned)f2bf(v1.x) | ((unsigned)f2bf(v1.y) << 16);
        w.w = (unsigned)f2bf(v1.z) | ((unsigned)f2bf(v1.w) << 16);
        int g = half * 4 + gi;
        *(uint4*)&lA[row * 64 + ((g ^ (row & 7)) * 8)] = w;
      }
    } else {
      const short* A = (const short*)Ap;
#pragma unroll
      for (int i = 0; i < 4; i++) {
        int c = wave * 4 + i;
        int row = c * 8 + (lane >> 3);
        int kg = (lane & 7) ^ (row & 7);
        gl2lds16(A + (size_t)(row0 + row) * K + k0 + kg * 8, lA + c * 512);
      }
    }
#pragma unroll
    for (int i = 0; i < 4; i++) {
      int c = wave * 4 + i;
      int row = c * 8 + (lane >> 3);
      int kg = (lane & 7) ^ (row & 7);
      gl2lds16(Bt + (size_t)(col0 + row) * K + k0 + kg * 8, lB + c * 512);
    }
    __syncthreads();
#pragma unroll
    for (int ks = 0; ks < 2; ks++) {
      s16x8 af[4], bf[4];
#pragma unroll
      for (int i = 0; i < 4; i++) {
        int R = qr + 16 * i + m;
        af[i] = *(const s16x8*)&lA[R * 64 + (((ks * 4 + q) ^ (R & 7)) * 8)];
        int RB = qc + 16 * i + m;
        bf[i] = *(const s16x8*)&lB[RB * 64 + (((ks * 4 + q) ^ (RB & 7)) * 8)];
      }
#pragma unroll
      for (int i = 0; i < 4; i++)
#pragma unroll
        for (int j = 0; j < 4; j++)
          acc[i][j] = __builtin_amdgcn_mfma_f32_16x16x32_bf16(af[i], bf[j], acc[i][j], 0, 0, 0);
    }
  }
#pragma unroll
  for (int i = 0; i < 4; i++) {
    int rbase = row0 + qr + 16 * i + q * 4;
#pragma unroll
    for (int j = 0; j < 4; j++) {
      int col = col0 + qc + 16 * j + m;
#pragma unroll
      for (int rr = 0; rr < 4; rr++) {
        int rg = rbase + rr;
        float v = acc[i][j][rr];
        if (MODE == 0) {
          v += bias[col]; v = fmaxf(v, 0.f);
          ((unsigned short*)Cp)[(size_t)rg * ldc + col] = f2bf(v);
        } else if (MODE == 1) {
          v *= dinv[rg % NN];
          ((unsigned short*)Cp)[(size_t)rg * ldc + col] = f2bf(v);
        } else {
          ((float*)Cp)[(size_t)rg * ldc + col] = v;
        }
      }
    }
  }
}

// ---------------- GCN aggregation: one wave per node, all T steps in flight ----------------
// 8 independent row loads per edge (one per t-slab) x2 edge unroll = 16 outstanding
// 256B loads per wave. Index list loaded lane-parallel, broadcast via shfl.
__global__ __launch_bounds__(256)
void agg_k(const unsigned int* __restrict__ Ms, unsigned int* __restrict__ Hout,
           const int* __restrict__ rp, const int* __restrict__ ci,
           const float* __restrict__ dinv, const float* __restrict__ bias)
{
  int v = blockIdx.x * 4 + (threadIdx.x >> 6);
  int lane = threadIdx.x & 63;
  const unsigned int* Ml = Ms + lane;

  float a0[TT], a1[TT];
#pragma unroll
  for (int t = 0; t < TT; t++) {                 // self-loop term
    unsigned int u = Ml[((size_t)t * NN + v) * 64];
    a0[t] = bflo(u); a1[t] = bfhi(u);
  }
  int e0 = rp[v], e1 = rp[v + 1];
  for (int chunk = e0; chunk < e1; chunk += 64) {
    int cnt = min(64, e1 - chunk);
    int myIdx = (lane < cnt) ? ci[chunk + lane] : 0;
    int j = 0;
    for (; j + 2 <= cnt; j += 2) {
      int s0 = __shfl(myIdx, j, 64);
      int s1 = __shfl(myIdx, j + 1, 64);
      unsigned int w0[TT], w1[TT];
#pragma unroll
      for (int t = 0; t < TT; t++) w0[t] = Ml[((size_t)t * NN + s0) * 64];
#pragma unroll
      for (int t = 0; t < TT; t++) w1[t] = Ml[((size_t)t * NN + s1) * 64];
#pragma unroll
      for (int t = 0; t < TT; t++) {
        a0[t] += bflo(w0[t]); a1[t] += bfhi(w0[t]);
        a0[t] += bflo(w1[t]); a1[t] += bfhi(w1[t]);
      }
    }
    if (j < cnt) {
      int s0 = __shfl(myIdx, j, 64);
      unsigned int w0[TT];
#pragma unroll
      for (int t = 0; t < TT; t++) w0[t] = Ml[((size_t)t * NN + s0) * 64];
#pragma unroll
      for (int t = 0; t < TT; t++) { a0[t] += bflo(w0[t]); a1[t] += bfhi(w0[t]); }
    }
  }
  float dv = dinv[v];
  float b0 = bias[lane * 2], b1 = bias[lane * 2 + 1];
#pragma unroll
  for (int t = 0; t < TT; t++) {
    float r0 = fmaxf(fmaf(dv, a0[t], b0), 0.f);
    float r1 = fmaxf(fmaf(dv, a1[t], b1), 0.f);
    Hout[((size_t)t * NN + v) * 64 + lane] =
        (unsigned int)f2bf(r0) | ((unsigned int)f2bf(r1) << 16);
  }
}

// ---------------- gather target embeddings -> TGT (bf16, [t][b][256]) ----------------
__global__ void gather_k(const unsigned int* __restrict__ h1, const unsigned int* __restrict__ h2,
                         const int* __restrict__ tix, unsigned int* __restrict__ TGT)
{
  int i = blockIdx.x * 256 + threadIdx.x;   // over 8*1024*128 dwords
  int dw = i & 127; int r = i >> 7; int b = r & 1023; int t = r >> 10;
  int node = tix[b];
  size_t src = ((size_t)t * NN + node) * 64 + (dw & 63);
  unsigned int val = (dw < 64) ? h1[src] : h2[src];
  TGT[(size_t)r * 128 + dw] = val;
}

// ---------------- GRU recurrence + attention (rows independent across B) ----------------
__global__ __launch_bounds__(256)
void gru_attn_k(const float* __restrict__ GI, const uint2* __restrict__ Whp,
                const float* __restrict__ b_ih, const float* __restrict__ b_hh,
                const float* __restrict__ attw, const float* __restrict__ attb,
                float* __restrict__ rep, float* __restrict__ out_attn)
{
  __shared__ float hbuf[2][128];
  __shared__ float red[2][2];
  __shared__ float sc[2][8];
  int tid = threadIdx.x;
  int r = tid >> 7, j = tid & 127;
  int lane = tid & 63, wv = tid >> 6;
  int b = blockIdx.x * 2 + r;
  hbuf[r][j] = 0.f;
  float bi0 = b_ih[j], bi1 = b_ih[128 + j], bi2 = b_ih[256 + j];
  float bh0 = b_hh[j], bh1 = b_hh[128 + j], bh2 = b_hh[256 + j];
  float aw = attw[j], ab = attb[0];
  float ht[8];
  __syncthreads();
  for (int t = 0; t < 8; t++) {
    const float* gi = GI + ((size_t)(t * 1024 + b)) * 384;
    float accr = bh0, accz = bh1, accg = bh2;
#pragma unroll 4
    for (int k = 0; k < 128; k++) {
      float hk = hbuf[r][k];
      uint2 wp = Whp[k * 128 + j];
      accr += hk * bflo(wp.x);
      accz += hk * bfhi(wp.x);
      accg += hk * bflo(wp.y);
    }
    float x0 = gi[j] + bi0, x1 = gi[128 + j] + bi1, x2 = gi[256 + j] + bi2;
    float rg = 1.f / (1.f + __expf(-(x0 + accr)));
    float z  = 1.f / (1.f + __expf(-(x1 + accz)));
    float g  = tanhf(x2 + rg * accg);
    float hp = hbuf[r][j];
    float hn = (1.f - z) * g + z * hp;
    __syncthreads();
    hbuf[r][j] = hn;
    float p = hn * aw;
    for (int off = 32; off; off >>= 1) p += __shfl_down(p, off, 64);
    if (lane == 0) red[wv >> 1][wv & 1] = p;
    __syncthreads();
    if (j == 0) sc[r][t] = tanhf(red[r][0] + red[r][1] + ab);
    ht[t] = hn;
  }
  __syncthreads();
  float s[8], mx = -1e30f;
#pragma unroll
  for (int t = 0; t < 8; t++) { s[t] = sc[r][t]; mx = fmaxf(mx, s[t]); }
  float sum = 0.f;
#pragma unroll
  for (int t = 0; t < 8; t++) { s[t] = __expf(s[t] - mx); sum += s[t]; }
  float inv = 1.f / sum;
  float rv = 0.f;
#pragma unroll
  for (int t = 0; t < 8; t++) rv += s[t] * inv * ht[t];
  rep[(size_t)b * 128 + j] = rv;
  if (j < 8) out_attn[b * 8 + j] = s[j] * inv;
}

// ---------------- final MLP ----------------
__global__ void pred_k(const float* __restrict__ rep, const float* __restrict__ w1,
                       const float* __restrict__ b1, const float* __restrict__ w2,
                       const float* __restrict__ b2, float* __restrict__ out)
{
  int bidx = blockIdx.x * 256 + threadIdx.x;
  if (bidx >= 1024) return;
  const float* rp = rep + (size_t)bidx * 128;
  float acc[16];
#pragma unroll
  for (int i = 0; i < 16; i++) acc[i] = b1[i];
  for (int k = 0; k < 128; k++) {
    float rv = rp[k];
#pragma unroll
    for (int i = 0; i < 16; i++) acc[i] += rv * w1[k * 16 + i];
  }
  float pv = b2[0];
#pragma unroll
  for (int i = 0; i < 16; i++) pv += fmaxf(acc[i], 0.f) * w2[i];
  out[bidx] = pv;
}

extern "C" void kernel_launch(void* const* d_in, const int* in_sizes, int n_in,
                              void* d_out, int out_size, void* d_ws, size_t ws_size,
                              hipStream_t stream)
{
  (void)in_sizes; (void)n_in; (void)out_size; (void)ws_size;
  const float* x      = (const float*)d_in[0];
  const int*   ei     = (const int*)d_in[1];
  const int*   tix    = (const int*)d_in[2];
  const float* proj_w = (const float*)d_in[3];
  const float* proj_b = (const float*)d_in[4];
  const float* gcn_w1 = (const float*)d_in[5];
  const float* gcn_b1 = (const float*)d_in[6];
  const float* gcn_w2 = (const float*)d_in[7];
  const float* gcn_b2 = (const float*)d_in[8];
  const float* w_ih   = (const float*)d_in[9];
  const float* w_hh   = (const float*)d_in[10];
  const float* b_ih   = (const float*)d_in[11];
  const float* b_hh   = (const float*)d_in[12];
  const float* attw   = (const float*)d_in[13];
  const float* attb   = (const float*)d_in[14];
  const float* pw1    = (const float*)d_in[15];
  const float* pb1    = (const float*)d_in[16];
  const float* pw2    = (const float*)d_in[17];
  const float* pb2    = (const float*)d_in[18];
  float* out = (float*)d_out;

  char* ws = (char*)d_ws;
  size_t off = 0;
  auto alloc = [&](size_t bytes) -> char* {
    char* p = ws + off; off += (bytes + 255) & ~(size_t)255; return p;
  };
  int*   counts = (int*)alloc((size_t)NN * 4);
  int*   fill   = (int*)alloc((size_t)NN * 4);
  int*   rp     = (int*)alloc((size_t)(NN + 1) * 4);
  float* dinv   = (float*)alloc((size_t)NN * 4);
  int*   ci     = (int*)alloc((size_t)EE * 4);
  unsigned short* projwt = (unsigned short*)alloc(128 * 256 * 2);
  unsigned short* w1t    = (unsigned short*)alloc(128 * 128 * 2);
  unsigned short* w2t    = (unsigned short*)alloc(128 * 128 * 2);
  unsigned short* wihb   = (unsigned short*)alloc(384 * 256 * 2);
  uint2* whhp            = (uint2*)alloc(128 * 128 * 8);
  unsigned int* TGT = (unsigned int*)alloc((size_t)8192 * 256 * 2);
  float* GI  = (float*)alloc((size_t)8192 * 384 * 4);
  float* rep = (float*)alloc((size_t)1024 * 128 * 4);
  unsigned short* bufA = (unsigned short*)alloc((size_t)ROWS * 128 * 2); // Hp, then h2
  unsigned short* bufB = (unsigned short*)alloc((size_t)ROWS * 128 * 2); // Ms1, then Ms2
  unsigned short* bufC = (unsigned short*)alloc((size_t)ROWS * 128 * 2); // h1

  const int* e_src = ei;
  const int* e_dst = ei + EE;

  prep_k<<<704, 256, 0, stream>>>(proj_w, gcn_w1, gcn_w2, w_ih, w_hh,
                                  projwt, w1t, w2t, wihb, whhp);
  init_k<<<157, 256, 0, stream>>>(counts, fill);
  count_k<<<2500, 256, 0, stream>>>(e_dst, counts);
  scan_k<<<1, 1024, 0, stream>>>(counts, rp, dinv);
  fill_k<<<2500, 256, 0, stream>>>(e_src, e_dst, rp, fill, ci);

  // proj: Hp = relu(x @ proj_w + b)   (fp32 A, bf16 out)
  gemm_k<1, 0><<<dim3(2500, 1), 256, 0, stream>>>(x, (const short*)projwt, bufA,
                                                  256, 128, proj_b, nullptr);
  // gcn1 matmul: Ms1 = dinv[row] * (Hp @ w1)
  gemm_k<0, 1><<<dim3(2500, 1), 256, 0, stream>>>(bufA, (const short*)w1t, bufB,
                                                  128, 128, nullptr, dinv);
  // gcn1 aggregate -> h1
  agg_k<<<10000, 256, 0, stream>>>((const unsigned int*)bufB, (unsigned int*)bufC,
                                   rp, ci, dinv, gcn_b1);
  // gcn2 matmul: Ms2 = dinv[row] * (h1 @ w2)
  gemm_k<0, 1><<<dim3(2500, 1), 256, 0, stream>>>(bufC, (const short*)w2t, bufB,
                                                  128, 128, nullptr, dinv);
  // gcn2 aggregate -> h2
  agg_k<<<10000, 256, 0, stream>>>((const unsigned int*)bufB, (unsigned int*)bufA,
                                   rp, ci, dinv, gcn_b2);
  // gather targets -> TGT
  gather_k<<<4096, 256, 0, stream>>>((const unsigned int*)bufC, (const unsigned int*)bufA,
                                     tix, TGT);
  // GI = TGT @ w_ih^T  (fp32 out)
  gemm_k<0, 2><<<dim3(64, 3), 256, 0, stream>>>(TGT, (const short*)wihb, GI,
                                                256, 384, nullptr, nullptr);
  // GRU + attention
  gru_attn_k<<<512, 256, 0, stream>>>(GI, whhp, b_ih, b_hh, attw, attb, rep, out + 1024);
  // prediction MLP
  pred_k<<<4, 256, 0, stream>>>(rep, pw1, pb1, pw2, pb2, out);
}

// Round 3
// 1164.948 us; speedup vs baseline: 1.4822x; 1.0546x over previous
//
#include <hip/hip_runtime.h>
#include <stdint.h>

#define TT 8
#define NN 40000
#define FF 256
#define EE 640000
#define BB 1024
#define ROWS 320000   // TT*NN

typedef __attribute__((ext_vector_type(8))) short s16x8;
typedef __attribute__((ext_vector_type(4))) float f32x4;

__device__ __forceinline__ unsigned short f2bf(float f){
  unsigned int u = __float_as_uint(f);
  u += 0x7fffu + ((u >> 16) & 1u);
  return (unsigned short)(u >> 16);
}
__device__ __forceinline__ float bflo(unsigned int u){ return __uint_as_float(u << 16); }
__device__ __forceinline__ float bfhi(unsigned int u){ return __uint_as_float(u & 0xffff0000u); }

// global -> LDS direct DMA, 16B per lane. LDS dest must be wave-uniform base + lane*16.
__device__ __forceinline__ void gl2lds16(const void* g, void* l){
  auto gp = reinterpret_cast<const unsigned int __attribute__((address_space(1)))*>(
      reinterpret_cast<uintptr_t>(g));
  auto lp = reinterpret_cast<unsigned int __attribute__((address_space(3)))*>(
      static_cast<unsigned int>(reinterpret_cast<uintptr_t>(l)));
  __builtin_amdgcn_global_load_lds(gp, lp, 16, 0, 0);
}

// ---------------- weight prep: transpose/convert to bf16 ----------------
__global__ void prep_k(const float* __restrict__ proj_w, const float* __restrict__ w1,
                       const float* __restrict__ w2, const float* __restrict__ wih,
                       const float* __restrict__ whh,
                       unsigned short* __restrict__ projwt, unsigned short* __restrict__ w1t,
                       unsigned short* __restrict__ w2t, unsigned short* __restrict__ wihb,
                       uint2* __restrict__ whhp)
{
  int i = blockIdx.x * 256 + threadIdx.x;
  if (i < 32768) {                      // projwt[p][f] = proj_w[f][p]
    int p = i >> 8, f = i & 255;
    projwt[i] = f2bf(proj_w[f * 128 + p]);
  } else if (i < 49152) {               // w1t[o][c] = w1[c][o]
    int k = i - 32768; int o = k >> 7, c = k & 127;
    w1t[k] = f2bf(w1[c * 128 + o]);
  } else if (i < 65536) {
    int k = i - 49152; int o = k >> 7, c = k & 127;
    w2t[k] = f2bf(w2[c * 128 + o]);
  } else if (i < 163840) {              // wihb = w_ih as-is (rows are output cols)
    int k = i - 65536;
    wihb[k] = f2bf(wih[k]);
  } else if (i < 180224) {              // whhp[k][j] = {whh[j][k], whh[128+j][k], whh[256+j][k], 0}
    int k = i - 163840; int kk = k >> 7, j = k & 127;
    unsigned int lo = (unsigned int)f2bf(whh[j * 128 + kk]) |
                      ((unsigned int)f2bf(whh[(128 + j) * 128 + kk]) << 16);
    unsigned int hi = (unsigned int)f2bf(whh[(256 + j) * 128 + kk]);
    whhp[k] = make_uint2(lo, hi);
  }
}

// ---------------- CSR build ----------------
__global__ void init_k(int* __restrict__ counts, int* __restrict__ fill){
  int i = blockIdx.x * 256 + threadIdx.x;
  if (i < NN) { counts[i] = 0; fill[i] = 0; }
}
__global__ void count_k(const int* __restrict__ dst, int* __restrict__ counts){
  int i = blockIdx.x * 256 + threadIdx.x;
  if (i < EE) atomicAdd(&counts[dst[i]], 1);
}
__global__ void scan_k(const int* __restrict__ counts, int* __restrict__ rp,
                       float* __restrict__ dinv)
{
  __shared__ int sums[1024];
  const int CH = 40;
  int t = threadIdx.x;
  int beg = t * CH, end = beg + CH; if (end > NN) end = NN; if (beg > NN) beg = NN;
  int s = 0;
  for (int i = beg; i < end; i++) s += counts[i];
  sums[t] = s;
  __syncthreads();
  for (int off = 1; off < 1024; off <<= 1) {
    int add = (t >= off) ? sums[t - off] : 0;
    __syncthreads();
    sums[t] += add;
    __syncthreads();
  }
  int run = sums[t] - s;   // exclusive prefix for this chunk
  for (int i = beg; i < end; i++) { rp[i] = run; run += counts[i]; }
  if (t == 1023) rp[NN] = sums[1023];
  for (int i = beg; i < end; i++) dinv[i] = rsqrtf((float)(counts[i] + 1));
}
__global__ void fill_k(const int* __restrict__ src, const int* __restrict__ dst,
                       const int* __restrict__ rp, int* __restrict__ fill,
                       int* __restrict__ ci)
{
  int i = blockIdx.x * 256 + threadIdx.x;
  if (i < EE) {
    int d = dst[i];
    int pos = rp[d] + atomicAdd(&fill[d], 1);
    ci[pos] = src[i];
  }
}

// ---------------- tiled MFMA GEMM: C[r][c] = sum_k A[r][k]*Bt[c][k] ----------------
// AF32: A is fp32 (converted to bf16 in stager); else A is bf16 (global_load_lds).
// MODE 0: bf16 out = relu(acc + bias[col]);  MODE 1: bf16 out = acc*dinv[row%NN];
// MODE 2: f32 out = acc.
template<int AF32, int MODE>
__global__ __launch_bounds__(256)
void gemm_k(const void* __restrict__ Ap, const short* __restrict__ Bt,
            void* __restrict__ Cp, int K, int ldc,
            const float* __restrict__ bias, const float* __restrict__ dinv)
{
  __shared__ short lA[128 * 64];
  __shared__ short lB[128 * 64];
  const int tid = threadIdx.x;
  const int lane = tid & 63, wave = tid >> 6;
  const int row0 = blockIdx.x * 128;
  const int col0 = blockIdx.y * 128;
  const int qr = (wave & 1) * 64, qc = (wave >> 1) * 64;
  const int m = lane & 15, q = lane >> 4;

  f32x4 acc[4][4];
#pragma unroll
  for (int i = 0; i < 4; i++)
#pragma unroll
    for (int j = 0; j < 4; j++) acc[i][j] = (f32x4){0.f, 0.f, 0.f, 0.f};

  for (int k0 = 0; k0 < K; k0 += 64) {
    __syncthreads();
    if (AF32) {
      const float* A = (const float*)Ap;
      int row = tid >> 1, half = tid & 1;
      const float* gp = A + (size_t)(row0 + row) * K + k0 + half * 32;
#pragma unroll
      for (int gi = 0; gi < 4; gi++) {
        float4 v0 = *(const float4*)(gp + gi * 8);
        float4 v1 = *(const float4*)(gp + gi * 8 + 4);
        uint4 w;
        w.x = (unsigned)f2bf(v0.x) | ((unsigned)f2bf(v0.y) << 16);
        w.y = (unsigned)f2bf(v0.z) | ((unsigned)f2bf(v0.w) << 16);
        w.z = (unsigned)f2bf(v1.x) | ((unsigned)f2bf(v1.y) << 16);
        w.w = (unsigned)f2bf(v1.z) | ((unsigned)f2bf(v1.w) << 16);
        int g = half * 4 + gi;
        *(uint4*)&lA[row * 64 + ((g ^ (row & 7)) * 8)] = w;
      }
    } else {
      const short* A = (const short*)Ap;
#pragma unroll
      for (int i = 0; i < 4; i++) {
        int c = wave * 4 + i;
        int row = c * 8 + (lane >> 3);
        int kg = (lane & 7) ^ (row & 7);
        gl2lds16(A + (size_t)(row0 + row) * K + k0 + kg * 8, lA + c * 512);
      }
    }
#pragma unroll
    for (int i = 0; i < 4; i++) {
      int c = wave * 4 + i;
      int row = c * 8 + (lane >> 3);
      int kg = (lane & 7) ^ (row & 7);
      gl2lds16(Bt + (size_t)(col0 + row) * K + k0 + kg * 8, lB + c * 512);
    }
    __syncthreads();
#pragma unroll
    for (int ks = 0; ks < 2; ks++) {
      s16x8 af[4], bf[4];
#pragma unroll
      for (int i = 0; i < 4; i++) {
        int R = qr + 16 * i + m;
        af[i] = *(const s16x8*)&lA[R * 64 + (((ks * 4 + q) ^ (R & 7)) * 8)];
        int RB = qc + 16 * i + m;
        bf[i] = *(const s16x8*)&lB[RB * 64 + (((ks * 4 + q) ^ (RB & 7)) * 8)];
      }
#pragma unroll
      for (int i = 0; i < 4; i++)
#pragma unroll
        for (int j = 0; j < 4; j++)
          acc[i][j] = __builtin_amdgcn_mfma_f32_16x16x32_bf16(af[i], bf[j], acc[i][j], 0, 0, 0);
    }
  }
#pragma unroll
  for (int i = 0; i < 4; i++) {
    int rbase = row0 + qr + 16 * i + q * 4;
#pragma unroll
    for (int j = 0; j < 4; j++) {
      int col = col0 + qc + 16 * j + m;
#pragma unroll
      for (int rr = 0; rr < 4; rr++) {
        int rg = rbase + rr;
        float v = acc[i][j][rr];
        if (MODE == 0) {
          v += bias[col]; v = fmaxf(v, 0.f);
          ((unsigned short*)Cp)[(size_t)rg * ldc + col] = f2bf(v);
        } else if (MODE == 1) {
          v *= dinv[rg % NN];
          ((unsigned short*)Cp)[(size_t)rg * ldc + col] = f2bf(v);
        } else {
          ((float*)Cp)[(size_t)rg * ldc + col] = v;
        }
      }
    }
  }
}

// ---------------- GCN aggregation: one wave per (t,node) -------------------
// Slab-local working set (blocks dispatched t-major => ~one 10 MB slab hot at
// a time) + lane-parallel index load + 4-edge unroll for memory-level
// parallelism. 8 VGPR accumul. footprint -> full occupancy.
__global__ __launch_bounds__(256)
void agg_k(const unsigned int* __restrict__ Ms, unsigned int* __restrict__ Hout,
           const int* __restrict__ rp, const int* __restrict__ ci,
           const float* __restrict__ dinv, const float* __restrict__ bias)
{
  int widx = blockIdx.x * 4 + (threadIdx.x >> 6);
  int lane = threadIdx.x & 63;
  int t = widx / NN;
  int v = widx - t * NN;
  const unsigned int* base = Ms + (size_t)t * NN * 64 + lane;

  unsigned int su = base[(size_t)v * 64];        // self-loop term
  float a0 = bflo(su), a1 = bfhi(su);

  int e0 = rp[v], e1 = rp[v + 1];
  for (int chunk = e0; chunk < e1; chunk += 64) {
    int cnt = min(64, e1 - chunk);
    int myIdx = (lane < cnt) ? ci[chunk + lane] : 0;
    int j = 0;
    for (; j + 4 <= cnt; j += 4) {
      int s0 = __shfl(myIdx, j, 64);
      int s1 = __shfl(myIdx, j + 1, 64);
      int s2 = __shfl(myIdx, j + 2, 64);
      int s3 = __shfl(myIdx, j + 3, 64);
      unsigned int w0 = base[(size_t)s0 * 64];
      unsigned int w1 = base[(size_t)s1 * 64];
      unsigned int w2 = base[(size_t)s2 * 64];
      unsigned int w3 = base[(size_t)s3 * 64];
      a0 += bflo(w0) + bflo(w1) + bflo(w2) + bflo(w3);
      a1 += bfhi(w0) + bfhi(w1) + bfhi(w2) + bfhi(w3);
    }
    for (; j < cnt; j++) {
      int s = __shfl(myIdx, j, 64);
      unsigned int w = base[(size_t)s * 64];
      a0 += bflo(w); a1 += bfhi(w);
    }
  }
  float dv = dinv[v];
  float b0 = bias[lane * 2], b1 = bias[lane * 2 + 1];
  float r0 = fmaxf(fmaf(dv, a0, b0), 0.f);
  float r1 = fmaxf(fmaf(dv, a1, b1), 0.f);
  Hout[(size_t)widx * 64 + lane] = (unsigned int)f2bf(r0) | ((unsigned int)f2bf(r1) << 16);
}

// ---------------- gather target embeddings -> TGT (bf16, [t][b][256]) ----------------
__global__ void gather_k(const unsigned int* __restrict__ h1, const unsigned int* __restrict__ h2,
                         const int* __restrict__ tix, unsigned int* __restrict__ TGT)
{
  int i = blockIdx.x * 256 + threadIdx.x;   // over 8*1024*128 dwords
  int dw = i & 127; int r = i >> 7; int b = r & 1023; int t = r >> 10;
  int node = tix[b];
  size_t src = ((size_t)t * NN + node) * 64 + (dw & 63);
  unsigned int val = (dw < 64) ? h1[src] : h2[src];
  TGT[(size_t)r * 128 + dw] = val;
}

// ---------------- GRU recurrence + attention (rows independent across B) ----------------
__global__ __launch_bounds__(256)
void gru_attn_k(const float* __restrict__ GI, const uint2* __restrict__ Whp,
                const float* __restrict__ b_ih, const float* __restrict__ b_hh,
                const float* __restrict__ attw, const float* __restrict__ attb,
                float* __restrict__ rep, float* __restrict__ out_attn)
{
  __shared__ float hbuf[2][128];
  __shared__ float red[2][2];
  __shared__ float sc[2][8];
  int tid = threadIdx.x;
  int r = tid >> 7, j = tid & 127;
  int lane = tid & 63, wv = tid >> 6;
  int b = blockIdx.x * 2 + r;
  hbuf[r][j] = 0.f;
  float bi0 = b_ih[j], bi1 = b_ih[128 + j], bi2 = b_ih[256 + j];
  float bh0 = b_hh[j], bh1 = b_hh[128 + j], bh2 = b_hh[256 + j];
  float aw = attw[j], ab = attb[0];
  float ht[8];
  __syncthreads();
  for (int t = 0; t < 8; t++) {
    const float* gi = GI + ((size_t)(t * 1024 + b)) * 384;
    float accr = bh0, accz = bh1, accg = bh2;
#pragma unroll 4
    for (int k = 0; k < 128; k++) {
      float hk = hbuf[r][k];
      uint2 wp = Whp[k * 128 + j];
      accr += hk * bflo(wp.x);
      accz += hk * bfhi(wp.x);
      accg += hk * bflo(wp.y);
    }
    float x0 = gi[j] + bi0, x1 = gi[128 + j] + bi1, x2 = gi[256 + j] + bi2;
    float rg = 1.f / (1.f + __expf(-(x0 + accr)));
    float z  = 1.f / (1.f + __expf(-(x1 + accz)));
    float g  = tanhf(x2 + rg * accg);
    float hp = hbuf[r][j];
    float hn = (1.f - z) * g + z * hp;
    __syncthreads();
    hbuf[r][j] = hn;
    float p = hn * aw;
    for (int off = 32; off; off >>= 1) p += __shfl_down(p, off, 64);
    if (lane == 0) red[wv >> 1][wv & 1] = p;
    __syncthreads();
    if (j == 0) sc[r][t] = tanhf(red[r][0] + red[r][1] + ab);
    ht[t] = hn;
  }
  __syncthreads();
  float s[8], mx = -1e30f;
#pragma unroll
  for (int t = 0; t < 8; t++) { s[t] = sc[r][t]; mx = fmaxf(mx, s[t]); }
  float sum = 0.f;
#pragma unroll
  for (int t = 0; t < 8; t++) { s[t] = __expf(s[t] - mx); sum += s[t]; }
  float inv = 1.f / sum;
  float rv = 0.f;
#pragma unroll
  for (int t = 0; t < 8; t++) rv += s[t] * inv * ht[t];
  rep[(size_t)b * 128 + j] = rv;
  if (j < 8) out_attn[b * 8 + j] = s[j] * inv;
}

// ---------------- final MLP ----------------
__global__ void pred_k(const float* __restrict__ rep, const float* __restrict__ w1,
                       const float* __restrict__ b1, const float* __restrict__ w2,
                       const float* __restrict__ b2, float* __restrict__ out)
{
  int bidx = blockIdx.x * 256 + threadIdx.x;
  if (bidx >= 1024) return;
  const float* rp = rep + (size_t)bidx * 128;
  float acc[16];
#pragma unroll
  for (int i = 0; i < 16; i++) acc[i] = b1[i];
  for (int k = 0; k < 128; k++) {
    float rv = rp[k];
#pragma unroll
    for (int i = 0; i < 16; i++) acc[i] += rv * w1[k * 16 + i];
  }
  float pv = b2[0];
#pragma unroll
  for (int i = 0; i < 16; i++) pv += fmaxf(acc[i], 0.f) * w2[i];
  out[bidx] = pv;
}

extern "C" void kernel_launch(void* const* d_in, const int* in_sizes, int n_in,
                              void* d_out, int out_size, void* d_ws, size_t ws_size,
                              hipStream_t stream)
{
  (void)in_sizes; (void)n_in; (void)out_size; (void)ws_size;
  const float* x      = (const float*)d_in[0];
  const int*   ei     = (const int*)d_in[1];
  const int*   tix    = (const int*)d_in[2];
  const float* proj_w = (const float*)d_in[3];
  const float* proj_b = (const float*)d_in[4];
  const float* gcn_w1 = (const float*)d_in[5];
  const float* gcn_b1 = (const float*)d_in[6];
  const float* gcn_w2 = (const float*)d_in[7];
  const float* gcn_b2 = (const float*)d_in[8];
  const float* w_ih   = (const float*)d_in[9];
  const float* w_hh   = (const float*)d_in[10];
  const float* b_ih   = (const float*)d_in[11];
  const float* b_hh   = (const float*)d_in[12];
  const float* attw   = (const float*)d_in[13];
  const float* attb   = (const float*)d_in[14];
  const float* pw1    = (const float*)d_in[15];
  const float* pb1    = (const float*)d_in[16];
  const float* pw2    = (const float*)d_in[17];
  const float* pb2    = (const float*)d_in[18];
  float* out = (float*)d_out;

  char* ws = (char*)d_ws;
  size_t off = 0;
  auto alloc = [&](size_t bytes) -> char* {
    char* p = ws + off; off += (bytes + 255) & ~(size_t)255; return p;
  };
  int*   counts = (int*)alloc((size_t)NN * 4);
  int*   fill   = (int*)alloc((size_t)NN * 4);
  int*   rp     = (int*)alloc((size_t)(NN + 1) * 4);
  float* dinv   = (float*)alloc((size_t)NN * 4);
  int*   ci     = (int*)alloc((size_t)EE * 4);
  unsigned short* projwt = (unsigned short*)alloc(128 * 256 * 2);
  unsigned short* w1t    = (unsigned short*)alloc(128 * 128 * 2);
  unsigned short* w2t    = (unsigned short*)alloc(128 * 128 * 2);
  unsigned short* wihb   = (unsigned short*)alloc(384 * 256 * 2);
  uint2* whhp            = (uint2*)alloc(128 * 128 * 8);
  unsigned int* TGT = (unsigned int*)alloc((size_t)8192 * 256 * 2);
  float* GI  = (float*)alloc((size_t)8192 * 384 * 4);
  float* rep = (float*)alloc((size_t)1024 * 128 * 4);
  unsigned short* bufA = (unsigned short*)alloc((size_t)ROWS * 128 * 2); // Hp, then h2
  unsigned short* bufB = (unsigned short*)alloc((size_t)ROWS * 128 * 2); // Ms1, then Ms2
  unsigned short* bufC = (unsigned short*)alloc((size_t)ROWS * 128 * 2); // h1

  const int* e_src = ei;
  const int* e_dst = ei + EE;

  prep_k<<<704, 256, 0, stream>>>(proj_w, gcn_w1, gcn_w2, w_ih, w_hh,
                                  projwt, w1t, w2t, wihb, whhp);
  init_k<<<157, 256, 0, stream>>>(counts, fill);
  count_k<<<2500, 256, 0, stream>>>(e_dst, counts);
  scan_k<<<1, 1024, 0, stream>>>(counts, rp, dinv);
  fill_k<<<2500, 256, 0, stream>>>(e_src, e_dst, rp, fill, ci);

  // proj: Hp = relu(x @ proj_w + b)   (fp32 A, bf16 out)
  gemm_k<1, 0><<<dim3(2500, 1), 256, 0, stream>>>(x, (const short*)projwt, bufA,
                                                  256, 128, proj_b, nullptr);
  // gcn1 matmul: Ms1 = dinv[row] * (Hp @ w1)
  gemm_k<0, 1><<<dim3(2500, 1), 256, 0, stream>>>(bufA, (const short*)w1t, bufB,
                                                  128, 128, nullptr, dinv);
  // gcn1 aggregate -> h1
  agg_k<<<80000, 256, 0, stream>>>((const unsigned int*)bufB, (unsigned int*)bufC,
                                   rp, ci, dinv, gcn_b1);
  // gcn2 matmul: Ms2 = dinv[row] * (h1 @ w2)
  gemm_k<0, 1><<<dim3(2500, 1), 256, 0, stream>>>(bufC, (const short*)w2t, bufB,
                                                  128, 128, nullptr, dinv);
  // gcn2 aggregate -> h2
  agg_k<<<80000, 256, 0, stream>>>((const unsigned int*)bufB, (unsigned int*)bufA,
                                   rp, ci, dinv, gcn_b2);
  // gather targets -> TGT
  gather_k<<<4096, 256, 0, stream>>>((const unsigned int*)bufC, (const unsigned int*)bufA,
                                     tix, TGT);
  // GI = TGT @ w_ih^T  (fp32 out)
  gemm_k<0, 2><<<dim3(64, 3), 256, 0, stream>>>(TGT, (const short*)wihb, GI,
                                                256, 384, nullptr, nullptr);
  // GRU + attention
  gru_attn_k<<<512, 256, 0, stream>>>(GI, whhp, b_ih, b_hh, attw, attb, rep, out + 1024);
  // prediction MLP
  pred_k<<<4, 256, 0, stream>>>(rep, pw1, pb1, pw2, pb2, out);
}